// Round 2
// baseline (1085.262 us; speedup 1.0000x reference)
//
#include <hip/hip_runtime.h>

#define SLEN 8192
#define BD   768
#define NH   12
#define NTOK 16384
#define HTOK 8192

typedef __bf16 bf16;
typedef __bf16 bf16x8 __attribute__((ext_vector_type(8)));
typedef float  floatx4 __attribute__((ext_vector_type(4)));

#define MFMA16(a, b, c) __builtin_amdgcn_mfma_f32_16x16x32_bf16((a), (b), (c), 0, 0, 0)

__device__ __forceinline__ int iclamp(int v, int lo, int hi) {
  return v < lo ? lo : (v > hi ? hi : v);
}

// async global->LDS DMA, 16B per lane; LDS dest = wave-uniform base + lane*16
__device__ __forceinline__ void gl2lds16(const bf16* g, bf16* l) {
  __builtin_amdgcn_global_load_lds(
      (const __attribute__((address_space(1))) void*)g,
      (__attribute__((address_space(3))) void*)l,
      16, 0, 0);
}

// ---------------- weight prep: Wt[n][k] = W[k][n] * scale (fp32 -> bf16) ----------------
__global__ __launch_bounds__(256) void k_prep_w(const float* __restrict__ W,
                                                bf16* __restrict__ Wt,
                                                int K, int N, float scale) {
  __shared__ float tile[32][33];
  const int tid = threadIdx.x;
  const int tx = tid & 31, ty = tid >> 5;  // 32 x 8
  const int n0 = blockIdx.x * 32, k0 = blockIdx.y * 32;
#pragma unroll
  for (int i = 0; i < 32; i += 8)
    tile[ty + i][tx] = W[(size_t)(k0 + ty + i) * N + n0 + tx];
  __syncthreads();
#pragma unroll
  for (int i = 0; i < 32; i += 8)
    Wt[(size_t)(n0 + ty + i) * K + k0 + tx] = (bf16)(tile[tx][ty + i] * scale);
}

__global__ void k_prep_qkv_bias(const float* __restrict__ bq, const float* __restrict__ bk,
                                const float* __restrict__ bv, float* __restrict__ out) {
  int i = blockIdx.x * 256 + threadIdx.x;
  if (i < 768) out[i] = bq[i] * 0.125f;          // fold 1/sqrt(64) into q
  else if (i < 1536) out[i] = bk[i - 768];
  else if (i < 2304) out[i] = bv[i - 1536];
}

// ---------------- block reduction over 256 threads (row of 768) ----------------
__device__ __forceinline__ float block_sum768(float v, float* red) {
#pragma unroll
  for (int off = 32; off > 0; off >>= 1) v += __shfl_down(v, off);
  __syncthreads();
  if ((threadIdx.x & 63) == 0) red[threadIdx.x >> 6] = v;
  __syncthreads();
  return red[0] + red[1] + red[2] + red[3];
}

// ---------------- LN(src) -> +pos+tt -> LN -> h (f32 + bf16) ----------------
__global__ __launch_bounds__(256) void k_ln_ln_emb(const float* __restrict__ src,
    const float* __restrict__ pos, const float* __restrict__ tt,
    const float* __restrict__ s1, const float* __restrict__ b1,
    const float* __restrict__ s2, const float* __restrict__ b2,
    float* __restrict__ hf, bf16* __restrict__ hb) {
  __shared__ float red[4];
  const int tid = threadIdx.x;
  const size_t row = blockIdx.x;
  const int sp = blockIdx.x & (SLEN - 1);
  const float* x = src + row * BD;
  float v0 = x[tid], v1 = x[tid + 256], v2 = x[tid + 512];
  const float mean = block_sum768(v0 + v1 + v2, red) * (1.f / 768.f);
  v0 -= mean; v1 -= mean; v2 -= mean;
  const float var = block_sum768(v0 * v0 + v1 * v1 + v2 * v2, red) * (1.f / 768.f);
  const float rstd = rsqrtf(var + 1e-5f);
  const float* pr = pos + (size_t)sp * BD;
  float y0 = v0 * rstd * s1[tid]       + b1[tid]       + pr[tid]       + tt[tid];
  float y1 = v1 * rstd * s1[tid + 256] + b1[tid + 256] + pr[tid + 256] + tt[tid + 256];
  float y2 = v2 * rstd * s1[tid + 512] + b1[tid + 512] + pr[tid + 512] + tt[tid + 512];
  const float mean2 = block_sum768(y0 + y1 + y2, red) * (1.f / 768.f);
  y0 -= mean2; y1 -= mean2; y2 -= mean2;
  const float var2 = block_sum768(y0 * y0 + y1 * y1 + y2 * y2, red) * (1.f / 768.f);
  const float rstd2 = rsqrtf(var2 + 1e-12f);
  float o0 = y0 * rstd2 * s2[tid]       + b2[tid];
  float o1 = y1 * rstd2 * s2[tid + 256] + b2[tid + 256];
  float o2 = y2 * rstd2 * s2[tid + 512] + b2[tid + 512];
  float* hr = hf + row * BD;
  bf16* hbr = hb + row * BD;
  hr[tid] = o0; hr[tid + 256] = o1; hr[tid + 512] = o2;
  hbr[tid] = (bf16)o0; hbr[tid + 256] = (bf16)o1; hbr[tid + 512] = (bf16)o2;
}

// ---------------- plain LN -> f32 + bf16 ----------------
__global__ __launch_bounds__(256) void k_ln(const float* __restrict__ x,
    const float* __restrict__ s, const float* __restrict__ b, float eps,
    float* __restrict__ of, bf16* __restrict__ ob) {
  __shared__ float red[4];
  const int tid = threadIdx.x;
  const size_t row = blockIdx.x;
  const float* xr = x + row * BD;
  float v0 = xr[tid], v1 = xr[tid + 256], v2 = xr[tid + 512];
  const float mean = block_sum768(v0 + v1 + v2, red) * (1.f / 768.f);
  v0 -= mean; v1 -= mean; v2 -= mean;
  const float var = block_sum768(v0 * v0 + v1 * v1 + v2 * v2, red) * (1.f / 768.f);
  const float rstd = rsqrtf(var + eps);
  float o0 = v0 * rstd * s[tid] + b[tid];
  float o1 = v1 * rstd * s[tid + 256] + b[tid + 256];
  float o2 = v2 * rstd * s[tid + 512] + b[tid + 512];
  float* ofr = of + row * BD; bf16* obr = ob + row * BD;
  ofr[tid] = o0; ofr[tid + 256] = o1; ofr[tid + 512] = o2;
  obr[tid] = (bf16)o0; obr[tid + 256] = (bf16)o1; obr[tid + 512] = (bf16)o2;
}

// ---------------- out = LN(y); src2 = src + out (f32); t = LN(src2) (bf16) ----------------
__global__ __launch_bounds__(256) void k_ln_add_ln(const float* __restrict__ y,
    const float* __restrict__ src,
    const float* __restrict__ so, const float* __restrict__ bo_,
    const float* __restrict__ s2, const float* __restrict__ b2,
    float* __restrict__ src2, bf16* __restrict__ tb) {
  __shared__ float red[4];
  const int tid = threadIdx.x;
  const size_t row = blockIdx.x;
  const float* xr = y + row * BD;
  float v0 = xr[tid], v1 = xr[tid + 256], v2 = xr[tid + 512];
  const float mean = block_sum768(v0 + v1 + v2, red) * (1.f / 768.f);
  v0 -= mean; v1 -= mean; v2 -= mean;
  const float var = block_sum768(v0 * v0 + v1 * v1 + v2 * v2, red) * (1.f / 768.f);
  const float rstd = rsqrtf(var + 1e-12f);
  const float* sr = src + row * BD;
  float u0 = sr[tid]       + v0 * rstd * so[tid]       + bo_[tid];
  float u1 = sr[tid + 256] + v1 * rstd * so[tid + 256] + bo_[tid + 256];
  float u2 = sr[tid + 512] + v2 * rstd * so[tid + 512] + bo_[tid + 512];
  float* s2r = src2 + row * BD;
  s2r[tid] = u0; s2r[tid + 256] = u1; s2r[tid + 512] = u2;
  const float mean2 = block_sum768(u0 + u1 + u2, red) * (1.f / 768.f);
  u0 -= mean2; u1 -= mean2; u2 -= mean2;
  const float var2 = block_sum768(u0 * u0 + u1 * u1 + u2 * u2, red) * (1.f / 768.f);
  const float rstd2 = rsqrtf(var2 + 1e-5f);
  bf16* tr = tb + row * BD;
  tr[tid]       = (bf16)(u0 * rstd2 * s2[tid]       + b2[tid]);
  tr[tid + 256] = (bf16)(u1 * rstd2 * s2[tid + 256] + b2[tid + 256]);
  tr[tid + 512] = (bf16)(u2 * rstd2 * s2[tid + 512] + b2[tid + 512]);
}

// ---------------- bf16 MFMA GEMM: C = A[MxK] @ Bt[NxK]^T + bias (+resid) (+act) ----------------
// 128x128 tile, 4 waves (2x2), each wave 64x64 = 4x4 MFMA tiles, BK=32.
// Double-buffered LDS (T3-minimum schedule): ONE barrier per K-step; stage(t+1) is
// issued right after the barrier so the 4 DMA loads fly across the whole
// ds_read+MFMA phase and are drained by the NEXT barrier's implicit vmcnt(0).
// LDS 32KB, VGPR<=128 -> 4 blocks/CU via __launch_bounds__(256,4).
template <int ACT, bool RES, bool OUTB>
__global__ __launch_bounds__(256, 4) void k_gemm(const bf16* __restrict__ A,
                                                 const bf16* __restrict__ Bt,
                                                 const float* __restrict__ bias,
                                                 const float* __restrict__ resid,
                                                 float* __restrict__ Cf,
                                                 bf16* __restrict__ Cb,
                                                 int M, int N, int K) {
  __shared__ __align__(16) bf16 As[2][128 * 32];
  __shared__ __align__(16) bf16 Bs[2][128 * 32];
  const int tid = threadIdx.x;
  const int lane = tid & 63, wave = tid >> 6;
  const int quad = lane >> 4, c = lane & 15;
  const int wr = wave >> 1, wc = wave & 1;
  const int n0 = blockIdx.x * 128, m0 = blockIdx.y * 128;

  // staging: wave w covers rows [w*32, w*32+32) of each tile, 2 DMA instrs each.
  const int rA0 = wave * 32 + (lane >> 2);
  const int rA1 = rA0 + 16;
  const int gch = (((lane & 3) ^ ((lane >> 3) & 3)) << 3);  // XOR chunk pre-swizzle (elems)
  const bf16* gA0 = A  + (size_t)(m0 + rA0) * K + gch;
  const bf16* gA1 = A  + (size_t)(m0 + rA1) * K + gch;
  const bf16* gB0 = Bt + (size_t)(n0 + rA0) * K + gch;
  const bf16* gB1 = Bt + (size_t)(n0 + rA1) * K + gch;
  const int ldst = wave * 1024;

  // loop-invariant LDS read offsets (k-chunk quad at swizzled position)
  const int xorq = ((quad ^ ((c >> 1) & 3)) << 3);
  int aOff[4], bOff[4];
#pragma unroll
  for (int i = 0; i < 4; ++i) {
    aOff[i] = (wr * 64 + i * 16 + c) * 32 + xorq;
    bOff[i] = (wc * 64 + i * 16 + c) * 32 + xorq;
  }

  floatx4 acc[4][4];
#pragma unroll
  for (int i = 0; i < 4; ++i)
#pragma unroll
    for (int j = 0; j < 4; ++j) acc[i][j] = floatx4{0.f, 0.f, 0.f, 0.f};

  auto stage = [&](int buf, int k0) {
    gl2lds16(gA0 + k0, &As[buf][ldst]);
    gl2lds16(gA1 + k0, &As[buf][ldst + 512]);
    gl2lds16(gB0 + k0, &Bs[buf][ldst]);
    gl2lds16(gB1 + k0, &Bs[buf][ldst + 512]);
  };

  stage(0, 0);
  int cur = 0;
  for (int k0 = 0; k0 < K; k0 += 32) {
    // implicit vmcnt(0)+lgkmcnt(0) drain: buf[cur] staged data visible to all
    // waves; all waves done reading buf[cur^1] (this iteration's stage target).
    __syncthreads();
    if (k0 + 32 < K) stage(cur ^ 1, k0 + 32);
    bf16x8 af[4], bfv[4];
#pragma unroll
    for (int i = 0; i < 4; ++i) af[i] = *(const bf16x8*)(&As[cur][aOff[i]]);
#pragma unroll
    for (int j = 0; j < 4; ++j) bfv[j] = *(const bf16x8*)(&Bs[cur][bOff[j]]);
#pragma unroll
    for (int i = 0; i < 4; ++i)
#pragma unroll
      for (int j = 0; j < 4; ++j)
        acc[i][j] = MFMA16(af[i], bfv[j], acc[i][j]);
    cur ^= 1;
  }

  const int rbase = m0 + wr * 64 + quad * 4;
  const int cbase = n0 + wc * 64 + c;
#pragma unroll
  for (int i = 0; i < 4; ++i) {
#pragma unroll
    for (int j = 0; j < 4; ++j) {
      const int col = cbase + j * 16;
      const float bc = bias[col];
#pragma unroll
      for (int r = 0; r < 4; ++r) {
        const int row = rbase + i * 16 + r;
        float v = acc[i][j][r] + bc;
        if (RES) v += resid[(size_t)row * N + col];
        if (ACT == 1) v = 0.5f * v * (1.f + erff(v * 0.70710678118654752f));
        if (ACT == 2) v = fmaxf(v, 0.f);
        if (OUTB) Cb[(size_t)row * N + col] = (bf16)v;
        else      Cf[(size_t)row * N + col] = v;
      }
    }
  }
}

// ---- V transpose per head (single batch): vt[h*64 + d][s] = qkv_b[s, 1536 + h*64 + d] ----
__global__ __launch_bounds__(256) void k_vtrans(const bf16* __restrict__ qkv_b, bf16* __restrict__ vt) {
  __shared__ bf16 tile[64][72];
  const int tid = threadIdx.x;
  const int blk = blockIdx.x;
  const int h  = blk >> 7;       // 0..11
  const int st = blk & 127;
  const int s0 = st * 64;
  {
    const int d = tid & 63, si4 = tid >> 6;
    const bf16* src = qkv_b + (size_t)s0 * 2304 + 1536 + h * 64 + d;
#pragma unroll
    for (int i = 0; i < 16; ++i) {
      int s = si4 * 16 + i;
      tile[s][d] = src[(size_t)s * 2304];
    }
  }
  __syncthreads();
  {
    const int s = tid & 63, di4 = tid >> 6;
#pragma unroll
    for (int i = 0; i < 16; ++i) {
      int d = di4 * 16 + i;
      vt[((size_t)(h * 64 + d)) * SLEN + s0 + s] = tile[s][d];
    }
  }
}

// ---------------- band attention (single batch), flash-style, cooperative block ----------------
__global__ __launch_bounds__(256, 4) void k_attn(const bf16* __restrict__ qkv_b,
                                                 const bf16* __restrict__ vt,
                                                 bf16* __restrict__ aout_b) {
  __shared__ __align__(16) bf16 Ks[2][64 * 64];
  __shared__ __align__(16) bf16 Vs[2][64 * 64];
  __shared__ __align__(16) bf16 Ps[4][16 * 64];
  const int tid  = threadIdx.x;
  const int wave = tid >> 6, lane = tid & 63;
  const int quad = lane >> 4, c = lane & 15;
  // XCD-chunked swizzle: 1536 blocks % 8 XCDs == 0
  const int blk0 = blockIdx.x;
  const int wg   = ((blk0 & 7) * 192) + (blk0 >> 3);
  const int h    = wg >> 7;           // 0..11
  const int st   = wg & 127;
  const int q0b  = st * 64;
  const int q0   = q0b + wave * 16;

  const bf16* qp = qkv_b + (size_t)(q0 + c) * 2304 + h * 64 + quad * 8;
  const bf16x8 aq0 = *(const bf16x8*)(qp);
  const bf16x8 aq1 = *(const bf16x8*)(qp + 32);

  const int srow  = lane >> 3;                       // 0..7
  const int chunk = ((lane & 7) ^ srow) << 3;        // XOR pre-swizzle on global source
  const int krow0 = wave * 16 + srow;

  const int xlo = (quad ^ (c & 7)) << 3;
  const int xhi = ((quad + 4) ^ (c & 7)) << 3;

  floatx4 o[4];
  float m[4], l[4];
#pragma unroll
  for (int r = 0; r < 4; ++r) {
    o[r] = floatx4{0.f, 0.f, 0.f, 0.f};
    m[r] = -1e30f; l[r] = 0.f;
  }
  bf16* Pw = &Ps[wave][0];

  const int t_lo = st < 4 ? 4 - st : 0;
  const int t_hi = st > 123 ? 132 - st : 9;

  auto stage = [&](int buf, int t) {
    const int kb  = q0b - 256 + 64 * t;
    const int kr0 = iclamp(kb + krow0, 0, SLEN - 1);
    const int kr1 = iclamp(kb + krow0 + 8, 0, SLEN - 1);
    gl2lds16(qkv_b + (size_t)kr0 * 2304 + 768 + h * 64 + chunk, &Ks[buf][wave * 1024]);
    gl2lds16(qkv_b + (size_t)kr1 * 2304 + 768 + h * 64 + chunk, &Ks[buf][wave * 1024 + 512]);
    const int kbc = iclamp(kb, 0, SLEN - 64);
    gl2lds16(vt + (size_t)(h * 64 + krow0) * SLEN + kbc + chunk, &Vs[buf][wave * 1024]);
    gl2lds16(vt + (size_t)(h * 64 + krow0 + 8) * SLEN + kbc + chunk, &Vs[buf][wave * 1024 + 512]);
  };

  int cur = 0;
  stage(0, t_lo);
  for (int t = t_lo; t < t_hi; ++t) {
    __syncthreads();
    if (t + 1 < t_hi) stage(cur ^ 1, t + 1);
    const int kb = q0b - 256 + 64 * t;
    const bf16* Kb = &Ks[cur][0];
    const bf16* Vb = &Vs[cur][0];

    floatx4 s[4];
#pragma unroll
    for (int i = 0; i < 4; ++i) s[i] = floatx4{0.f, 0.f, 0.f, 0.f};
#pragma unroll
    for (int ks = 0; ks < 4; ++ks) {
      const bf16* kr = Kb + (ks * 16 + c) * 64;
      s[ks] = MFMA16(aq0, *(const bf16x8*)(kr + xlo), s[ks]);
      s[ks] = MFMA16(aq1, *(const bf16x8*)(kr + xhi), s[ks]);
    }
    if (t == 0 || t == 8) {
#pragma unroll
      for (int ks = 0; ks < 4; ++ks)
#pragma unroll
        for (int r = 0; r < 4; ++r) {
          int d = (kb + ks * 16 + c) - (q0 + quad * 4 + r);
          d = d < 0 ? -d : d;
          if (d > 256) s[ks][r] = -INFINITY;
        }
    }

    float tm[4], rs[4];
#pragma unroll
    for (int r = 0; r < 4; ++r)
      tm[r] = fmaxf(fmaxf(s[0][r], s[1][r]), fmaxf(s[2][r], s[3][r]));
#pragma unroll
    for (int off = 1; off < 16; off <<= 1)
#pragma unroll
      for (int r = 0; r < 4; ++r) tm[r] = fmaxf(tm[r], __shfl_xor(tm[r], off));
#pragma unroll
    for (int r = 0; r < 4; ++r) {
      const float mn = fmaxf(m[r], tm[r]);
      const float al = __expf(m[r] - mn);
      m[r] = mn;
      float sum = 0.f;
#pragma unroll
      for (int ks = 0; ks < 4; ++ks) { s[ks][r] = __expf(s[ks][r] - mn); sum += s[ks][r]; }
      rs[r] = sum;
      l[r] *= al;
#pragma unroll
      for (int n = 0; n < 4; ++n) o[n][r] *= al;
    }
#pragma unroll
    for (int off = 1; off < 16; off <<= 1)
#pragma unroll
      for (int r = 0; r < 4; ++r) rs[r] += __shfl_xor(rs[r], off);
#pragma unroll
    for (int r = 0; r < 4; ++r) l[r] += rs[r];

#pragma unroll
    for (int ks = 0; ks < 4; ++ks)
#pragma unroll
      for (int r = 0; r < 4; ++r) {
        const int prow = quad * 4 + r;
        const int col  = ks * 16 + c;
        Pw[prow * 64 + ((((col >> 3) ^ (prow & 7)) << 3) | (col & 7))] = (bf16)s[ks][r];
      }
    asm volatile("s_waitcnt lgkmcnt(0)" ::: "memory");
    const bf16x8 pa0 = *(const bf16x8*)(Pw + c * 64 + xlo);
    const bf16x8 pa1 = *(const bf16x8*)(Pw + c * 64 + xhi);
#pragma unroll
    for (int n = 0; n < 4; ++n) {
      const bf16* vr = Vb + (n * 16 + c) * 64;
      o[n] = MFMA16(pa0, *(const bf16x8*)(vr + xlo), o[n]);
      o[n] = MFMA16(pa1, *(const bf16x8*)(vr + xhi), o[n]);
    }
    cur ^= 1;
  }

#pragma unroll
  for (int r = 0; r < 4; ++r) {
    const float inv = 1.f / l[r];
    const size_t orow = (size_t)(q0 + quad * 4 + r) * BD + h * 64;
#pragma unroll
    for (int n = 0; n < 4; ++n)
      aout_b[orow + n * 16 + c] = (bf16)(o[n][r] * inv);
  }
}

extern "C" void kernel_launch(void* const* d_in, const int* in_sizes, int n_in,
                              void* d_out, int out_size, void* d_ws, size_t ws_size,
                              hipStream_t stream) {
  (void)in_sizes; (void)n_in; (void)out_size; (void)ws_size;
  const float* src     = (const float*)d_in[0];
  const float* pos_emb = (const float*)d_in[1];
  const float* tt_emb  = (const float*)d_in[2];
  const float* emb_s   = (const float*)d_in[3];
  const float* emb_b   = (const float*)d_in[4];
  const float* wq      = (const float*)d_in[5];
  const float* bq      = (const float*)d_in[6];
  const float* wk      = (const float*)d_in[7];
  const float* bk      = (const float*)d_in[8];
  const float* wv      = (const float*)d_in[9];
  const float* bv      = (const float*)d_in[10];
  const float* wo      = (const float*)d_in[11];
  const float* bo      = (const float*)d_in[12];
  const float* atn_s   = (const float*)d_in[13];
  const float* atn_b   = (const float*)d_in[14];
  const float* wi      = (const float*)d_in[15];
  const float* bi      = (const float*)d_in[16];
  const float* wo2     = (const float*)d_in[17];
  const float* bo2     = (const float*)d_in[18];
  const float* out_s   = (const float*)d_in[19];
  const float* out_b   = (const float*)d_in[20];
  const float* n1_s    = (const float*)d_in[21];
  const float* n1_b    = (const float*)d_in[22];
  const float* n2_s    = (const float*)d_in[23];
  const float* n2_b    = (const float*)d_in[24];
  const float* w1      = (const float*)d_in[25];
  const float* b1      = (const float*)d_in[26];
  const float* w2      = (const float*)d_in[27];
  const float* b2      = (const float*)d_in[28];

  char* ws = (char*)d_ws;
  size_t off = 0;
  auto alloc = [&](size_t bytes) {
    char* p = ws + off;
    off += (bytes + 255) & ~(size_t)255;
    return p;
  };

  // ---- persistent weights (~23.6 MB) ----
  bf16* qkvt  = (bf16*)alloc((size_t)2304 * 768 * 2);
  bf16* wot   = (bf16*)alloc((size_t)768 * 768 * 2);
  bf16* wit   = (bf16*)alloc((size_t)3072 * 768 * 2);
  bf16* wo2t  = (bf16*)alloc((size_t)768 * 3072 * 2);
  bf16* w1t   = (bf16*)alloc((size_t)3072 * 768 * 2);
  bf16* w2t   = (bf16*)alloc((size_t)768 * 3072 * 2);
  float* qkvb = (float*)alloc((size_t)2304 * 4);
  // ---- reusable regions (total ws ~155 MB) ----
  char* R1 = alloc((size_t)NTOK * BD * 4);                 // f32: h -> h2 -> src2
  char* R2 = alloc((size_t)NTOK * BD * 2);                 // bf16: hb -> h2b -> tb
  char* R3 = alloc((size_t)HTOK * 2304 * 2                 // per-batch qkv
                 + (size_t)NH * 64 * SLEN * 2              // per-batch vt
                 + (size_t)HTOK * BD * 2);                 // per-batch aout

  float* h_f   = (float*)R1;
  bf16*  hb    = (bf16*)R2;
  bf16*  qkvB  = (bf16*)R3;
  bf16*  vtB   = (bf16*)(R3 + (size_t)HTOK * 2304 * 2);
  bf16*  aoutB = (bf16*)(R3 + (size_t)HTOK * 2304 * 2 + (size_t)NH * 64 * SLEN * 2);
  float* y1    = (float*)d_out;
  float* h2f   = (float*)R1;
  bf16*  h2b   = (bf16*)R2;
  bf16*  interC= (bf16*)R3;
  float* y2    = (float*)d_out;
  float* src2  = (float*)R1;
  bf16*  tb    = (bf16*)R2;
  bf16*  ff1C  = (bf16*)R3;
  float* outp  = (float*)d_out;

  dim3 blk(256);
  // weight conversion (scale folds q /sqrt(64))
  k_prep_w<<<dim3(24, 24), blk, 0, stream>>>(wq, qkvt,                 768, 768, 0.125f);
  k_prep_w<<<dim3(24, 24), blk, 0, stream>>>(wk, qkvt + 768 * 768,     768, 768, 1.f);
  k_prep_w<<<dim3(24, 24), blk, 0, stream>>>(wv, qkvt + 2 * 768 * 768, 768, 768, 1.f);
  k_prep_w<<<dim3(24, 24), blk, 0, stream>>>(wo, wot,                  768, 768, 1.f);
  k_prep_w<<<dim3(96, 24), blk, 0, stream>>>(wi, wit,    768, 3072, 1.f);
  k_prep_w<<<dim3(24, 96), blk, 0, stream>>>(wo2, wo2t, 3072, 768,  1.f);
  k_prep_w<<<dim3(96, 24), blk, 0, stream>>>(w1, w1t,    768, 3072, 1.f);
  k_prep_w<<<dim3(24, 96), blk, 0, stream>>>(w2, w2t,   3072, 768,  1.f);
  k_prep_qkv_bias<<<dim3(9), blk, 0, stream>>>(bq, bk, bv, qkvb);

  // hidden = LN(src); h = LN(hidden + pos + tt)
  k_ln_ln_emb<<<dim3(NTOK), blk, 0, stream>>>(src, pos_emb, tt_emb, n1_s, n1_b,
                                              emb_s, emb_b, h_f, hb);
  // attention path, one batch at a time
  for (int b = 0; b < 2; ++b) {
    const size_t tok0 = (size_t)b * HTOK;
    k_gemm<0, false, true><<<dim3(18, 64), blk, 0, stream>>>(
        hb + tok0 * BD, qkvt, qkvb, nullptr, nullptr, qkvB, HTOK, 2304, 768);
    k_vtrans<<<dim3(NH * 128), blk, 0, stream>>>(qkvB, vtB);
    k_attn<<<dim3(NH * 128), blk, 0, stream>>>(qkvB, vtB, aoutB);
    k_gemm<0, true, false><<<dim3(6, 64), blk, 0, stream>>>(
        aoutB, wot, bo, h_f + tok0 * BD, y1 + tok0 * BD, nullptr, HTOK, 768, 768);
  }
  // h2 = LN(y1)
  k_ln<<<dim3(NTOK), blk, 0, stream>>>(y1, atn_s, atn_b, 1e-12f, h2f, h2b);
  // FFN, half the tokens at a time
  for (int cchunk = 0; cchunk < 2; ++cchunk) {
    const size_t tok0 = (size_t)cchunk * HTOK;
    k_gemm<1, false, true><<<dim3(24, 64), blk, 0, stream>>>(
        h2b + tok0 * BD, wit, bi, nullptr, nullptr, interC, HTOK, 3072, 768);
    k_gemm<0, true, false><<<dim3(6, 64), blk, 0, stream>>>(
        interC, wo2t, bo2, h2f + tok0 * BD, y2 + tok0 * BD, nullptr, HTOK, 768, 3072);
  }
  // out = LN(y2); src2 = src + out; t = LN(src2)
  k_ln_add_ln<<<dim3(NTOK), blk, 0, stream>>>(y2, src, out_s, out_b, n2_s, n2_b, src2, tb);
  // second FFN block
  for (int cchunk = 0; cchunk < 2; ++cchunk) {
    const size_t tok0 = (size_t)cchunk * HTOK;
    k_gemm<2, false, true><<<dim3(24, 64), blk, 0, stream>>>(
        tb + tok0 * BD, w1t, b1, nullptr, nullptr, ff1C, HTOK, 3072, 768);
    k_gemm<0, true, false><<<dim3(6, 64), blk, 0, stream>>>(
        ff1C, w2t, b2, src2 + tok0 * BD, outp + tok0 * BD, nullptr, HTOK, 768, 3072);
  }
}

// Round 3
// 1051.966 us; speedup vs baseline: 1.0317x; 1.0317x over previous
//
#include <hip/hip_runtime.h>

#define SLEN 8192
#define BD   768
#define NH   12
#define NTOK 16384
#define HTOK 8192

typedef __bf16 bf16;
typedef __bf16 bf16x8 __attribute__((ext_vector_type(8)));
typedef float  floatx4 __attribute__((ext_vector_type(4)));

#define MFMA16(a, b, c) __builtin_amdgcn_mfma_f32_16x16x32_bf16((a), (b), (c), 0, 0, 0)

__device__ __forceinline__ int iclamp(int v, int lo, int hi) {
  return v < lo ? lo : (v > hi ? hi : v);
}

// async global->LDS DMA, 16B per lane; LDS dest = wave-uniform base + lane*16
__device__ __forceinline__ void gl2lds16(const bf16* g, bf16* l) {
  __builtin_amdgcn_global_load_lds(
      (const __attribute__((address_space(1))) void*)g,
      (__attribute__((address_space(3))) void*)l,
      16, 0, 0);
}

// ---------------- weight prep: Wt[n][k] = W[k][n] * scale (fp32 -> bf16) ----------------
__global__ __launch_bounds__(256) void k_prep_w(const float* __restrict__ W,
                                                bf16* __restrict__ Wt,
                                                int K, int N, float scale) {
  __shared__ float tile[32][33];
  const int tid = threadIdx.x;
  const int tx = tid & 31, ty = tid >> 5;  // 32 x 8
  const int n0 = blockIdx.x * 32, k0 = blockIdx.y * 32;
#pragma unroll
  for (int i = 0; i < 32; i += 8)
    tile[ty + i][tx] = W[(size_t)(k0 + ty + i) * N + n0 + tx];
  __syncthreads();
#pragma unroll
  for (int i = 0; i < 32; i += 8)
    Wt[(size_t)(n0 + ty + i) * K + k0 + tx] = (bf16)(tile[tx][ty + i] * scale);
}

__global__ void k_prep_qkv_bias(const float* __restrict__ bq, const float* __restrict__ bk,
                                const float* __restrict__ bv, float* __restrict__ out) {
  int i = blockIdx.x * 256 + threadIdx.x;
  if (i < 768) out[i] = bq[i] * 0.125f;          // fold 1/sqrt(64) into q
  else if (i < 1536) out[i] = bk[i - 768];
  else if (i < 2304) out[i] = bv[i - 1536];
}

// ---------------- block reduction over 256 threads (row of 768) ----------------
__device__ __forceinline__ float block_sum768(float v, float* red) {
#pragma unroll
  for (int off = 32; off > 0; off >>= 1) v += __shfl_down(v, off);
  __syncthreads();
  if ((threadIdx.x & 63) == 0) red[threadIdx.x >> 6] = v;
  __syncthreads();
  return red[0] + red[1] + red[2] + red[3];
}

// ---------------- LN(src) -> +pos+tt -> LN -> h (f32 + bf16) ----------------
__global__ __launch_bounds__(256) void k_ln_ln_emb(const float* __restrict__ src,
    const float* __restrict__ pos, const float* __restrict__ tt,
    const float* __restrict__ s1, const float* __restrict__ b1,
    const float* __restrict__ s2, const float* __restrict__ b2,
    float* __restrict__ hf, bf16* __restrict__ hb) {
  __shared__ float red[4];
  const int tid = threadIdx.x;
  const size_t row = blockIdx.x;
  const int sp = blockIdx.x & (SLEN - 1);
  const float* x = src + row * BD;
  float v0 = x[tid], v1 = x[tid + 256], v2 = x[tid + 512];
  const float mean = block_sum768(v0 + v1 + v2, red) * (1.f / 768.f);
  v0 -= mean; v1 -= mean; v2 -= mean;
  const float var = block_sum768(v0 * v0 + v1 * v1 + v2 * v2, red) * (1.f / 768.f);
  const float rstd = rsqrtf(var + 1e-5f);
  const float* pr = pos + (size_t)sp * BD;
  float y0 = v0 * rstd * s1[tid]       + b1[tid]       + pr[tid]       + tt[tid];
  float y1 = v1 * rstd * s1[tid + 256] + b1[tid + 256] + pr[tid + 256] + tt[tid + 256];
  float y2 = v2 * rstd * s1[tid + 512] + b1[tid + 512] + pr[tid + 512] + tt[tid + 512];
  const float mean2 = block_sum768(y0 + y1 + y2, red) * (1.f / 768.f);
  y0 -= mean2; y1 -= mean2; y2 -= mean2;
  const float var2 = block_sum768(y0 * y0 + y1 * y1 + y2 * y2, red) * (1.f / 768.f);
  const float rstd2 = rsqrtf(var2 + 1e-12f);
  float o0 = y0 * rstd2 * s2[tid]       + b2[tid];
  float o1 = y1 * rstd2 * s2[tid + 256] + b2[tid + 256];
  float o2 = y2 * rstd2 * s2[tid + 512] + b2[tid + 512];
  float* hr = hf + row * BD;
  bf16* hbr = hb + row * BD;
  hr[tid] = o0; hr[tid + 256] = o1; hr[tid + 512] = o2;
  hbr[tid] = (bf16)o0; hbr[tid + 256] = (bf16)o1; hbr[tid + 512] = (bf16)o2;
}

// ---------------- plain LN -> f32 + bf16 ----------------
__global__ __launch_bounds__(256) void k_ln(const float* __restrict__ x,
    const float* __restrict__ s, const float* __restrict__ b, float eps,
    float* __restrict__ of, bf16* __restrict__ ob) {
  __shared__ float red[4];
  const int tid = threadIdx.x;
  const size_t row = blockIdx.x;
  const float* xr = x + row * BD;
  float v0 = xr[tid], v1 = xr[tid + 256], v2 = xr[tid + 512];
  const float mean = block_sum768(v0 + v1 + v2, red) * (1.f / 768.f);
  v0 -= mean; v1 -= mean; v2 -= mean;
  const float var = block_sum768(v0 * v0 + v1 * v1 + v2 * v2, red) * (1.f / 768.f);
  const float rstd = rsqrtf(var + eps);
  float o0 = v0 * rstd * s[tid] + b[tid];
  float o1 = v1 * rstd * s[tid + 256] + b[tid + 256];
  float o2 = v2 * rstd * s[tid + 512] + b[tid + 512];
  float* ofr = of + row * BD; bf16* obr = ob + row * BD;
  ofr[tid] = o0; ofr[tid + 256] = o1; ofr[tid + 512] = o2;
  obr[tid] = (bf16)o0; obr[tid + 256] = (bf16)o1; obr[tid + 512] = (bf16)o2;
}

// ---------------- out = LN(y); src2 = src + out (f32); t = LN(src2) (bf16) ----------------
__global__ __launch_bounds__(256) void k_ln_add_ln(const float* __restrict__ y,
    const float* __restrict__ src,
    const float* __restrict__ so, const float* __restrict__ bo_,
    const float* __restrict__ s2, const float* __restrict__ b2,
    float* __restrict__ src2, bf16* __restrict__ tb) {
  __shared__ float red[4];
  const int tid = threadIdx.x;
  const size_t row = blockIdx.x;
  const float* xr = y + row * BD;
  float v0 = xr[tid], v1 = xr[tid + 256], v2 = xr[tid + 512];
  const float mean = block_sum768(v0 + v1 + v2, red) * (1.f / 768.f);
  v0 -= mean; v1 -= mean; v2 -= mean;
  const float var = block_sum768(v0 * v0 + v1 * v1 + v2 * v2, red) * (1.f / 768.f);
  const float rstd = rsqrtf(var + 1e-12f);
  const float* sr = src + row * BD;
  float u0 = sr[tid]       + v0 * rstd * so[tid]       + bo_[tid];
  float u1 = sr[tid + 256] + v1 * rstd * so[tid + 256] + bo_[tid + 256];
  float u2 = sr[tid + 512] + v2 * rstd * so[tid + 512] + bo_[tid + 512];
  float* s2r = src2 + row * BD;
  s2r[tid] = u0; s2r[tid + 256] = u1; s2r[tid + 512] = u2;
  const float mean2 = block_sum768(u0 + u1 + u2, red) * (1.f / 768.f);
  u0 -= mean2; u1 -= mean2; u2 -= mean2;
  const float var2 = block_sum768(u0 * u0 + u1 * u1 + u2 * u2, red) * (1.f / 768.f);
  const float rstd2 = rsqrtf(var2 + 1e-5f);
  bf16* tr = tb + row * BD;
  tr[tid]       = (bf16)(u0 * rstd2 * s2[tid]       + b2[tid]);
  tr[tid + 256] = (bf16)(u1 * rstd2 * s2[tid + 256] + b2[tid + 256]);
  tr[tid + 512] = (bf16)(u2 * rstd2 * s2[tid + 512] + b2[tid + 512]);
}

// ---------------- bf16 MFMA GEMM: C = A[MxK] @ Bt[NxK]^T + bias (+resid) (+act) ----------------
// Tile BM x 128, 4 waves, BK=32, double-buffered LDS (one barrier per K-step; stage(t+1)
// issued right after the barrier, drained by the NEXT barrier's implicit vmcnt(0)).
//   BM=128: waves 2x2, each 64x64 (acc[4][4]); fat GEMMs; MINW=2 (occupancy revert — r2
//           showed 3 blocks/CU regressed fat dispatches 83->108us).
//   BM=64 : waves 1x4, each 64x32 (acc[4][2]); thin N=768 GEMMs -> grid 768 blocks = 3/CU
//           exact packing (no 1.5-blocks/CU makespan tail).
// Bijective XCD-chunked swizzle (all grids %8==0): consecutive work-ids (sharing an
// A-row-slice) land on one XCD's L2 -> cuts A re-fetch across N-tiles.
template <int BM, int MINW, int ACT, bool RES, bool OUTB>
__global__ __launch_bounds__(256, MINW) void k_gemm(const bf16* __restrict__ A,
                                                    const bf16* __restrict__ Bt,
                                                    const float* __restrict__ bias,
                                                    const float* __restrict__ resid,
                                                    float* __restrict__ Cf,
                                                    bf16* __restrict__ Cb,
                                                    int M, int N, int K) {
  __shared__ __align__(16) bf16 As[2][BM * 32];
  __shared__ __align__(16) bf16 Bs[2][128 * 32];
  constexpr int NJ = (BM == 128) ? 4 : 2;
  const int tid = threadIdx.x;
  const int lane = tid & 63, wave = tid >> 6;
  const int quad = lane >> 4, c = lane & 15;
  // XCD-chunked bijective swizzle (grid % 8 == 0 at every call site)
  const int gx = gridDim.x;
  const int G  = gx * gridDim.y;
  const int bid = blockIdx.y * gx + blockIdx.x;
  const int wgid = (bid & 7) * (G >> 3) + (bid >> 3);
  const int bx = wgid % gx, by = wgid / gx;
  const int n0 = bx * 128, m0 = by * BM;

  const int wrb = (BM == 128) ? (wave >> 1) * 64 : 0;       // wave M base
  const int wcb = (BM == 128) ? (wave & 1) * 64 : wave * 32; // wave N base

  // staging: 16-row 1KB DMA instrs; lane i covers row i>>2, chunk i&3 (XOR pre-swizzled)
  const int srow = lane >> 2;                                // 0..15
  const int gch  = (((lane & 3) ^ ((lane >> 3) & 3)) << 3);  // elems
  const bf16* gA0;
  const bf16* gA1 = nullptr;
  int ldsA0, ldsA1 = 0;
  if constexpr (BM == 128) {
    gA0 = A + (size_t)(m0 + wave * 32 + srow) * K + gch;
    gA1 = A + (size_t)(m0 + wave * 32 + 16 + srow) * K + gch;
    ldsA0 = wave * 1024; ldsA1 = wave * 1024 + 512;
  } else {
    gA0 = A + (size_t)(m0 + wave * 16 + srow) * K + gch;
    ldsA0 = wave * 512;
  }
  const bf16* gB0 = Bt + (size_t)(n0 + wave * 32 + srow) * K + gch;
  const bf16* gB1 = Bt + (size_t)(n0 + wave * 32 + 16 + srow) * K + gch;
  const int ldsB0 = wave * 1024, ldsB1 = wave * 1024 + 512;

  // loop-invariant LDS read offsets (k-chunk quad at swizzled position; key=(row>>1)&3)
  const int xorq = ((quad ^ ((c >> 1) & 3)) << 3);
  int aOff[4], bOff[NJ];
#pragma unroll
  for (int i = 0; i < 4; ++i) aOff[i] = (wrb + i * 16 + c) * 32 + xorq;
#pragma unroll
  for (int j = 0; j < NJ; ++j) bOff[j] = (wcb + j * 16 + c) * 32 + xorq;

  floatx4 acc[4][NJ];
#pragma unroll
  for (int i = 0; i < 4; ++i)
#pragma unroll
    for (int j = 0; j < NJ; ++j) acc[i][j] = floatx4{0.f, 0.f, 0.f, 0.f};

  auto stage = [&](int buf, int k0) {
    gl2lds16(gA0 + k0, &As[buf][ldsA0]);
    if constexpr (BM == 128) gl2lds16(gA1 + k0, &As[buf][ldsA1]);
    gl2lds16(gB0 + k0, &Bs[buf][ldsB0]);
    gl2lds16(gB1 + k0, &Bs[buf][ldsB1]);
  };

  stage(0, 0);
  int cur = 0;
  for (int k0 = 0; k0 < K; k0 += 32) {
    // implicit vmcnt(0)+lgkmcnt(0) drain: buf[cur] staged data visible to all
    // waves; all waves done reading buf[cur^1] (this iteration's stage target).
    __syncthreads();
    if (k0 + 32 < K) stage(cur ^ 1, k0 + 32);
    bf16x8 af[4], bfv[NJ];
#pragma unroll
    for (int i = 0; i < 4; ++i) af[i] = *(const bf16x8*)(&As[cur][aOff[i]]);
#pragma unroll
    for (int j = 0; j < NJ; ++j) bfv[j] = *(const bf16x8*)(&Bs[cur][bOff[j]]);
#pragma unroll
    for (int i = 0; i < 4; ++i)
#pragma unroll
      for (int j = 0; j < NJ; ++j)
        acc[i][j] = MFMA16(af[i], bfv[j], acc[i][j]);
    cur ^= 1;
  }

  const int rbase = m0 + wrb + quad * 4;
  const int cbase = n0 + wcb + c;
#pragma unroll
  for (int i = 0; i < 4; ++i) {
#pragma unroll
    for (int j = 0; j < NJ; ++j) {
      const int col = cbase + j * 16;
      const float bc = bias[col];
#pragma unroll
      for (int r = 0; r < 4; ++r) {
        const int row = rbase + i * 16 + r;
        float v = acc[i][j][r] + bc;
        if (RES) v += resid[(size_t)row * N + col];
        if (ACT == 1) v = 0.5f * v * (1.f + erff(v * 0.70710678118654752f));
        if (ACT == 2) v = fmaxf(v, 0.f);
        if (OUTB) Cb[(size_t)row * N + col] = (bf16)v;
        else      Cf[(size_t)row * N + col] = v;
      }
    }
  }
  (void)M;
}

// ---- V transpose per head (single batch): vt[h*64 + d][s] = qkv_b[s, 1536 + h*64 + d] ----
__global__ __launch_bounds__(256) void k_vtrans(const bf16* __restrict__ qkv_b, bf16* __restrict__ vt) {
  __shared__ bf16 tile[64][72];
  const int tid = threadIdx.x;
  const int blk = blockIdx.x;
  const int h  = blk >> 7;       // 0..11
  const int st = blk & 127;
  const int s0 = st * 64;
  {
    const int d = tid & 63, si4 = tid >> 6;
    const bf16* src = qkv_b + (size_t)s0 * 2304 + 1536 + h * 64 + d;
#pragma unroll
    for (int i = 0; i < 16; ++i) {
      int s = si4 * 16 + i;
      tile[s][d] = src[(size_t)s * 2304];
    }
  }
  __syncthreads();
  {
    const int s = tid & 63, di4 = tid >> 6;
#pragma unroll
    for (int i = 0; i < 16; ++i) {
      int d = di4 * 16 + i;
      vt[((size_t)(h * 64 + d)) * SLEN + s0 + s] = tile[s][d];
    }
  }
}

// ---------------- band attention (single batch), flash-style, cooperative block ----------------
__global__ __launch_bounds__(256, 4) void k_attn(const bf16* __restrict__ qkv_b,
                                                 const bf16* __restrict__ vt,
                                                 bf16* __restrict__ aout_b) {
  __shared__ __align__(16) bf16 Ks[2][64 * 64];
  __shared__ __align__(16) bf16 Vs[2][64 * 64];
  __shared__ __align__(16) bf16 Ps[4][16 * 64];
  const int tid  = threadIdx.x;
  const int wave = tid >> 6, lane = tid & 63;
  const int quad = lane >> 4, c = lane & 15;
  // XCD-chunked swizzle: 1536 blocks % 8 XCDs == 0
  const int blk0 = blockIdx.x;
  const int wg   = ((blk0 & 7) * 192) + (blk0 >> 3);
  const int h    = wg >> 7;           // 0..11
  const int st   = wg & 127;
  const int q0b  = st * 64;
  const int q0   = q0b + wave * 16;

  const bf16* qp = qkv_b + (size_t)(q0 + c) * 2304 + h * 64 + quad * 8;
  const bf16x8 aq0 = *(const bf16x8*)(qp);
  const bf16x8 aq1 = *(const bf16x8*)(qp + 32);

  const int srow  = lane >> 3;                       // 0..7
  const int chunk = ((lane & 7) ^ srow) << 3;        // XOR pre-swizzle on global source
  const int krow0 = wave * 16 + srow;

  const int xlo = (quad ^ (c & 7)) << 3;
  const int xhi = ((quad + 4) ^ (c & 7)) << 3;

  floatx4 o[4];
  float m[4], l[4];
#pragma unroll
  for (int r = 0; r < 4; ++r) {
    o[r] = floatx4{0.f, 0.f, 0.f, 0.f};
    m[r] = -1e30f; l[r] = 0.f;
  }
  bf16* Pw = &Ps[wave][0];

  const int t_lo = st < 4 ? 4 - st : 0;
  const int t_hi = st > 123 ? 132 - st : 9;

  auto stage = [&](int buf, int t) {
    const int kb  = q0b - 256 + 64 * t;
    const int kr0 = iclamp(kb + krow0, 0, SLEN - 1);
    const int kr1 = iclamp(kb + krow0 + 8, 0, SLEN - 1);
    gl2lds16(qkv_b + (size_t)kr0 * 2304 + 768 + h * 64 + chunk, &Ks[buf][wave * 1024]);
    gl2lds16(qkv_b + (size_t)kr1 * 2304 + 768 + h * 64 + chunk, &Ks[buf][wave * 1024 + 512]);
    const int kbc = iclamp(kb, 0, SLEN - 64);
    gl2lds16(vt + (size_t)(h * 64 + krow0) * SLEN + kbc + chunk, &Vs[buf][wave * 1024]);
    gl2lds16(vt + (size_t)(h * 64 + krow0 + 8) * SLEN + kbc + chunk, &Vs[buf][wave * 1024 + 512]);
  };

  int cur = 0;
  stage(0, t_lo);
  for (int t = t_lo; t < t_hi; ++t) {
    __syncthreads();
    if (t + 1 < t_hi) stage(cur ^ 1, t + 1);
    const int kb = q0b - 256 + 64 * t;
    const bf16* Kb = &Ks[cur][0];
    const bf16* Vb = &Vs[cur][0];

    floatx4 s[4];
#pragma unroll
    for (int i = 0; i < 4; ++i) s[i] = floatx4{0.f, 0.f, 0.f, 0.f};
#pragma unroll
    for (int ks = 0; ks < 4; ++ks) {
      const bf16* kr = Kb + (ks * 16 + c) * 64;
      s[ks] = MFMA16(aq0, *(const bf16x8*)(kr + xlo), s[ks]);
      s[ks] = MFMA16(aq1, *(const bf16x8*)(kr + xhi), s[ks]);
    }
    if (t == 0 || t == 8) {
#pragma unroll
      for (int ks = 0; ks < 4; ++ks)
#pragma unroll
        for (int r = 0; r < 4; ++r) {
          int d = (kb + ks * 16 + c) - (q0 + quad * 4 + r);
          d = d < 0 ? -d : d;
          if (d > 256) s[ks][r] = -INFINITY;
        }
    }

    float tm[4], rs[4];
#pragma unroll
    for (int r = 0; r < 4; ++r)
      tm[r] = fmaxf(fmaxf(s[0][r], s[1][r]), fmaxf(s[2][r], s[3][r]));
#pragma unroll
    for (int off = 1; off < 16; off <<= 1)
#pragma unroll
      for (int r = 0; r < 4; ++r) tm[r] = fmaxf(tm[r], __shfl_xor(tm[r], off));
#pragma unroll
    for (int r = 0; r < 4; ++r) {
      const float mn = fmaxf(m[r], tm[r]);
      const float al = __expf(m[r] - mn);
      m[r] = mn;
      float sum = 0.f;
#pragma unroll
      for (int ks = 0; ks < 4; ++ks) { s[ks][r] = __expf(s[ks][r] - mn); sum += s[ks][r]; }
      rs[r] = sum;
      l[r] *= al;
#pragma unroll
      for (int n = 0; n < 4; ++n) o[n][r] *= al;
    }
#pragma unroll
    for (int off = 1; off < 16; off <<= 1)
#pragma unroll
      for (int r = 0; r < 4; ++r) rs[r] += __shfl_xor(rs[r], off);
#pragma unroll
    for (int r = 0; r < 4; ++r) l[r] += rs[r];

#pragma unroll
    for (int ks = 0; ks < 4; ++ks)
#pragma unroll
      for (int r = 0; r < 4; ++r) {
        const int prow = quad * 4 + r;
        const int col  = ks * 16 + c;
        Pw[prow * 64 + ((((col >> 3) ^ (prow & 7)) << 3) | (col & 7))] = (bf16)s[ks][r];
      }
    asm volatile("s_waitcnt lgkmcnt(0)" ::: "memory");
    const bf16x8 pa0 = *(const bf16x8*)(Pw + c * 64 + xlo);
    const bf16x8 pa1 = *(const bf16x8*)(Pw + c * 64 + xhi);
#pragma unroll
    for (int n = 0; n < 4; ++n) {
      const bf16* vr = Vb + (n * 16 + c) * 64;
      o[n] = MFMA16(pa0, *(const bf16x8*)(vr + xlo), o[n]);
      o[n] = MFMA16(pa1, *(const bf16x8*)(vr + xhi), o[n]);
    }
    cur ^= 1;
  }

#pragma unroll
  for (int r = 0; r < 4; ++r) {
    const float inv = 1.f / l[r];
    const size_t orow = (size_t)(q0 + quad * 4 + r) * BD + h * 64;
#pragma unroll
    for (int n = 0; n < 4; ++n)
      aout_b[orow + n * 16 + c] = (bf16)(o[n][r] * inv);
  }
}

extern "C" void kernel_launch(void* const* d_in, const int* in_sizes, int n_in,
                              void* d_out, int out_size, void* d_ws, size_t ws_size,
                              hipStream_t stream) {
  (void)in_sizes; (void)n_in; (void)out_size; (void)ws_size;
  const float* src     = (const float*)d_in[0];
  const float* pos_emb = (const float*)d_in[1];
  const float* tt_emb  = (const float*)d_in[2];
  const float* emb_s   = (const float*)d_in[3];
  const float* emb_b   = (const float*)d_in[4];
  const float* wq      = (const float*)d_in[5];
  const float* bq      = (const float*)d_in[6];
  const float* wk      = (const float*)d_in[7];
  const float* bk      = (const float*)d_in[8];
  const float* wv      = (const float*)d_in[9];
  const float* bv      = (const float*)d_in[10];
  const float* wo      = (const float*)d_in[11];
  const float* bo      = (const float*)d_in[12];
  const float* atn_s   = (const float*)d_in[13];
  const float* atn_b   = (const float*)d_in[14];
  const float* wi      = (const float*)d_in[15];
  const float* bi      = (const float*)d_in[16];
  const float* wo2     = (const float*)d_in[17];
  const float* bo2     = (const float*)d_in[18];
  const float* out_s   = (const float*)d_in[19];
  const float* out_b   = (const float*)d_in[20];
  const float* n1_s    = (const float*)d_in[21];
  const float* n1_b    = (const float*)d_in[22];
  const float* n2_s    = (const float*)d_in[23];
  const float* n2_b    = (const float*)d_in[24];
  const float* w1      = (const float*)d_in[25];
  const float* b1      = (const float*)d_in[26];
  const float* w2      = (const float*)d_in[27];
  const float* b2      = (const float*)d_in[28];

  char* ws = (char*)d_ws;
  size_t off = 0;
  auto alloc = [&](size_t bytes) {
    char* p = ws + off;
    off += (bytes + 255) & ~(size_t)255;
    return p;
  };

  // ---- persistent weights (~23.6 MB) ----
  bf16* qkvt  = (bf16*)alloc((size_t)2304 * 768 * 2);
  bf16* wot   = (bf16*)alloc((size_t)768 * 768 * 2);
  bf16* wit   = (bf16*)alloc((size_t)3072 * 768 * 2);
  bf16* wo2t  = (bf16*)alloc((size_t)768 * 3072 * 2);
  bf16* w1t   = (bf16*)alloc((size_t)3072 * 768 * 2);
  bf16* w2t   = (bf16*)alloc((size_t)768 * 3072 * 2);
  float* qkvb = (float*)alloc((size_t)2304 * 4);
  // ---- reusable regions (total ws ~155 MB) ----
  char* R1 = alloc((size_t)NTOK * BD * 4);                 // f32: h -> h2 -> src2
  char* R2 = alloc((size_t)NTOK * BD * 2);                 // bf16: hb -> h2b -> tb
  char* R3 = alloc((size_t)HTOK * 2304 * 2                 // per-batch qkv
                 + (size_t)NH * 64 * SLEN * 2              // per-batch vt
                 + (size_t)HTOK * BD * 2);                 // per-batch aout

  float* h_f   = (float*)R1;
  bf16*  hb    = (bf16*)R2;
  bf16*  qkvB  = (bf16*)R3;
  bf16*  vtB   = (bf16*)(R3 + (size_t)HTOK * 2304 * 2);
  bf16*  aoutB = (bf16*)(R3 + (size_t)HTOK * 2304 * 2 + (size_t)NH * 64 * SLEN * 2);
  float* y1    = (float*)d_out;
  float* h2f   = (float*)R1;
  bf16*  h2b   = (bf16*)R2;
  bf16*  interC= (bf16*)R3;
  float* y2    = (float*)d_out;
  float* src2  = (float*)R1;
  bf16*  tb    = (bf16*)R2;
  bf16*  ff1C  = (bf16*)R3;
  float* outp  = (float*)d_out;

  dim3 blk(256);
  // weight conversion (scale folds q /sqrt(64))
  k_prep_w<<<dim3(24, 24), blk, 0, stream>>>(wq, qkvt,                 768, 768, 0.125f);
  k_prep_w<<<dim3(24, 24), blk, 0, stream>>>(wk, qkvt + 768 * 768,     768, 768, 1.f);
  k_prep_w<<<dim3(24, 24), blk, 0, stream>>>(wv, qkvt + 2 * 768 * 768, 768, 768, 1.f);
  k_prep_w<<<dim3(24, 24), blk, 0, stream>>>(wo, wot,                  768, 768, 1.f);
  k_prep_w<<<dim3(96, 24), blk, 0, stream>>>(wi, wit,    768, 3072, 1.f);
  k_prep_w<<<dim3(24, 96), blk, 0, stream>>>(wo2, wo2t, 3072, 768,  1.f);
  k_prep_w<<<dim3(96, 24), blk, 0, stream>>>(w1, w1t,    768, 3072, 1.f);
  k_prep_w<<<dim3(24, 96), blk, 0, stream>>>(w2, w2t,   3072, 768,  1.f);
  k_prep_qkv_bias<<<dim3(9), blk, 0, stream>>>(bq, bk, bv, qkvb);

  // hidden = LN(src); h = LN(hidden + pos + tt)
  k_ln_ln_emb<<<dim3(NTOK), blk, 0, stream>>>(src, pos_emb, tt_emb, n1_s, n1_b,
                                              emb_s, emb_b, h_f, hb);
  // attention path, one batch at a time
  for (int b = 0; b < 2; ++b) {
    const size_t tok0 = (size_t)b * HTOK;
    k_gemm<128, 2, 0, false, true><<<dim3(18, 64), blk, 0, stream>>>(
        hb + tok0 * BD, qkvt, qkvb, nullptr, nullptr, qkvB, HTOK, 2304, 768);
    k_vtrans<<<dim3(NH * 128), blk, 0, stream>>>(qkvB, vtB);
    k_attn<<<dim3(NH * 128), blk, 0, stream>>>(qkvB, vtB, aoutB);
    k_gemm<64, 4, 0, true, false><<<dim3(6, 128), blk, 0, stream>>>(
        aoutB, wot, bo, h_f + tok0 * BD, y1 + tok0 * BD, nullptr, HTOK, 768, 768);
  }
  // h2 = LN(y1)
  k_ln<<<dim3(NTOK), blk, 0, stream>>>(y1, atn_s, atn_b, 1e-12f, h2f, h2b);
  // FFN, half the tokens at a time
  for (int cchunk = 0; cchunk < 2; ++cchunk) {
    const size_t tok0 = (size_t)cchunk * HTOK;
    k_gemm<128, 2, 1, false, true><<<dim3(24, 64), blk, 0, stream>>>(
        h2b + tok0 * BD, wit, bi, nullptr, nullptr, interC, HTOK, 3072, 768);
    k_gemm<64, 4, 0, true, false><<<dim3(6, 128), blk, 0, stream>>>(
        interC, wo2t, bo2, h2f + tok0 * BD, y2 + tok0 * BD, nullptr, HTOK, 768, 3072);
  }
  // out = LN(y2); src2 = src + out; t = LN(src2)
  k_ln_add_ln<<<dim3(NTOK), blk, 0, stream>>>(y2, src, out_s, out_b, n2_s, n2_b, src2, tb);
  // second FFN block
  for (int cchunk = 0; cchunk < 2; ++cchunk) {
    const size_t tok0 = (size_t)cchunk * HTOK;
    k_gemm<128, 2, 2, false, true><<<dim3(24, 64), blk, 0, stream>>>(
        tb + tok0 * BD, w1t, b1, nullptr, nullptr, ff1C, HTOK, 3072, 768);
    k_gemm<64, 4, 0, true, false><<<dim3(6, 128), blk, 0, stream>>>(
        ff1C, w2t, b2, src2 + tok0 * BD, outp + tok0 * BD, nullptr, HTOK, 768, 3072);
  }
}

// Round 4
// 966.431 us; speedup vs baseline: 1.1230x; 1.0885x over previous
//
#include <hip/hip_runtime.h>

#define SLEN 8192
#define BD   768
#define NH   12
#define NTOK 16384
#define HTOK 8192

typedef __bf16 bf16;
typedef __bf16 bf16x8 __attribute__((ext_vector_type(8)));
typedef float  floatx4 __attribute__((ext_vector_type(4)));

#define MFMA16(a, b, c) __builtin_amdgcn_mfma_f32_16x16x32_bf16((a), (b), (c), 0, 0, 0)

__device__ __forceinline__ int iclamp(int v, int lo, int hi) {
  return v < lo ? lo : (v > hi ? hi : v);
}

// async global->LDS DMA, 16B per lane; LDS dest = wave-uniform base + lane*16
__device__ __forceinline__ void gl2lds16(const bf16* g, bf16* l) {
  __builtin_amdgcn_global_load_lds(
      (const __attribute__((address_space(1))) void*)g,
      (__attribute__((address_space(3))) void*)l,
      16, 0, 0);
}

// ---------------- weight prep: Wt[n][k] = W[k][n] * scale (fp32 -> bf16) ----------------
__global__ __launch_bounds__(256) void k_prep_w(const float* __restrict__ W,
                                                bf16* __restrict__ Wt,
                                                int K, int N, float scale) {
  __shared__ float tile[32][33];
  const int tid = threadIdx.x;
  const int tx = tid & 31, ty = tid >> 5;  // 32 x 8
  const int n0 = blockIdx.x * 32, k0 = blockIdx.y * 32;
#pragma unroll
  for (int i = 0; i < 32; i += 8)
    tile[ty + i][tx] = W[(size_t)(k0 + ty + i) * N + n0 + tx];
  __syncthreads();
#pragma unroll
  for (int i = 0; i < 32; i += 8)
    Wt[(size_t)(n0 + ty + i) * K + k0 + tx] = (bf16)(tile[tx][ty + i] * scale);
}

__global__ void k_prep_qkv_bias(const float* __restrict__ bq, const float* __restrict__ bk,
                                const float* __restrict__ bv, float* __restrict__ out) {
  int i = blockIdx.x * 256 + threadIdx.x;
  if (i < 768) out[i] = bq[i] * 0.125f;          // fold 1/sqrt(64) into q
  else if (i < 1536) out[i] = bk[i - 768];
  else if (i < 2304) out[i] = bv[i - 1536];
}

// ---------------- block reduction over 256 threads (row of 768) ----------------
__device__ __forceinline__ float block_sum768(float v, float* red) {
#pragma unroll
  for (int off = 32; off > 0; off >>= 1) v += __shfl_down(v, off);
  __syncthreads();
  if ((threadIdx.x & 63) == 0) red[threadIdx.x >> 6] = v;
  __syncthreads();
  return red[0] + red[1] + red[2] + red[3];
}

// ---------------- LN(src) -> +pos+tt -> LN -> h (f32 + bf16) ----------------
__global__ __launch_bounds__(256) void k_ln_ln_emb(const float* __restrict__ src,
    const float* __restrict__ pos, const float* __restrict__ tt,
    const float* __restrict__ s1, const float* __restrict__ b1,
    const float* __restrict__ s2, const float* __restrict__ b2,
    float* __restrict__ hf, bf16* __restrict__ hb) {
  __shared__ float red[4];
  const int tid = threadIdx.x;
  const size_t row = blockIdx.x;
  const int sp = blockIdx.x & (SLEN - 1);
  const float* x = src + row * BD;
  float v0 = x[tid], v1 = x[tid + 256], v2 = x[tid + 512];
  const float mean = block_sum768(v0 + v1 + v2, red) * (1.f / 768.f);
  v0 -= mean; v1 -= mean; v2 -= mean;
  const float var = block_sum768(v0 * v0 + v1 * v1 + v2 * v2, red) * (1.f / 768.f);
  const float rstd = rsqrtf(var + 1e-5f);
  const float* pr = pos + (size_t)sp * BD;
  float y0 = v0 * rstd * s1[tid]       + b1[tid]       + pr[tid]       + tt[tid];
  float y1 = v1 * rstd * s1[tid + 256] + b1[tid + 256] + pr[tid + 256] + tt[tid + 256];
  float y2 = v2 * rstd * s1[tid + 512] + b1[tid + 512] + pr[tid + 512] + tt[tid + 512];
  const float mean2 = block_sum768(y0 + y1 + y2, red) * (1.f / 768.f);
  y0 -= mean2; y1 -= mean2; y2 -= mean2;
  const float var2 = block_sum768(y0 * y0 + y1 * y1 + y2 * y2, red) * (1.f / 768.f);
  const float rstd2 = rsqrtf(var2 + 1e-12f);
  float o0 = y0 * rstd2 * s2[tid]       + b2[tid];
  float o1 = y1 * rstd2 * s2[tid + 256] + b2[tid + 256];
  float o2 = y2 * rstd2 * s2[tid + 512] + b2[tid + 512];
  float* hr = hf + row * BD;
  bf16* hbr = hb + row * BD;
  hr[tid] = o0; hr[tid + 256] = o1; hr[tid + 512] = o2;
  hbr[tid] = (bf16)o0; hbr[tid + 256] = (bf16)o1; hbr[tid + 512] = (bf16)o2;
}

// ---------------- plain LN -> f32 + bf16 ----------------
__global__ __launch_bounds__(256) void k_ln(const float* __restrict__ x,
    const float* __restrict__ s, const float* __restrict__ b, float eps,
    float* __restrict__ of, bf16* __restrict__ ob) {
  __shared__ float red[4];
  const int tid = threadIdx.x;
  const size_t row = blockIdx.x;
  const float* xr = x + row * BD;
  float v0 = xr[tid], v1 = xr[tid + 256], v2 = xr[tid + 512];
  const float mean = block_sum768(v0 + v1 + v2, red) * (1.f / 768.f);
  v0 -= mean; v1 -= mean; v2 -= mean;
  const float var = block_sum768(v0 * v0 + v1 * v1 + v2 * v2, red) * (1.f / 768.f);
  const float rstd = rsqrtf(var + eps);
  float o0 = v0 * rstd * s[tid] + b[tid];
  float o1 = v1 * rstd * s[tid + 256] + b[tid + 256];
  float o2 = v2 * rstd * s[tid + 512] + b[tid + 512];
  float* ofr = of + row * BD; bf16* obr = ob + row * BD;
  ofr[tid] = o0; ofr[tid + 256] = o1; ofr[tid + 512] = o2;
  obr[tid] = (bf16)o0; obr[tid + 256] = (bf16)o1; obr[tid + 512] = (bf16)o2;
}

// ---------------- out = LN(y); src2 = src + out (f32); t = LN(src2) (bf16) ----------------
__global__ __launch_bounds__(256) void k_ln_add_ln(const float* __restrict__ y,
    const float* __restrict__ src,
    const float* __restrict__ so, const float* __restrict__ bo_,
    const float* __restrict__ s2, const float* __restrict__ b2,
    float* __restrict__ src2, bf16* __restrict__ tb) {
  __shared__ float red[4];
  const int tid = threadIdx.x;
  const size_t row = blockIdx.x;
  const float* xr = y + row * BD;
  float v0 = xr[tid], v1 = xr[tid + 256], v2 = xr[tid + 512];
  const float mean = block_sum768(v0 + v1 + v2, red) * (1.f / 768.f);
  v0 -= mean; v1 -= mean; v2 -= mean;
  const float var = block_sum768(v0 * v0 + v1 * v1 + v2 * v2, red) * (1.f / 768.f);
  const float rstd = rsqrtf(var + 1e-12f);
  const float* sr = src + row * BD;
  float u0 = sr[tid]       + v0 * rstd * so[tid]       + bo_[tid];
  float u1 = sr[tid + 256] + v1 * rstd * so[tid + 256] + bo_[tid + 256];
  float u2 = sr[tid + 512] + v2 * rstd * so[tid + 512] + bo_[tid + 512];
  float* s2r = src2 + row * BD;
  s2r[tid] = u0; s2r[tid + 256] = u1; s2r[tid + 512] = u2;
  const float mean2 = block_sum768(u0 + u1 + u2, red) * (1.f / 768.f);
  u0 -= mean2; u1 -= mean2; u2 -= mean2;
  const float var2 = block_sum768(u0 * u0 + u1 * u1 + u2 * u2, red) * (1.f / 768.f);
  const float rstd2 = rsqrtf(var2 + 1e-5f);
  bf16* tr = tb + row * BD;
  tr[tid]       = (bf16)(u0 * rstd2 * s2[tid]       + b2[tid]);
  tr[tid + 256] = (bf16)(u1 * rstd2 * s2[tid + 256] + b2[tid + 256]);
  tr[tid + 512] = (bf16)(u2 * rstd2 * s2[tid + 512] + b2[tid + 512]);
}

// ---------------- bf16 MFMA GEMM: C = A[MxK] @ Bt[NxK]^T + bias (+resid) (+act) ----------------
// Tile BM x 128, 4 waves, BK=64 (r4: doubled from 32 — r3 showed 2050 cyc/K-step vs
// ~155 cyc of MFMA work; bigger steps halve barrier drains and double per-step compute
// so co-resident blocks' MFMA covers the DMA latency). Double-buffered LDS, one barrier
// per K-step; stage(t+1) issued right after the barrier, drained by the NEXT barrier.
//   BM=128: waves 2x2, each 64x64; LDS 64KB -> 2 blocks/CU (fat was already minw=2).
//   BM=64 : waves 1x4, each 64x32; LDS 48KB -> 3 blocks/CU; thin N=768 grid 768 = 3/CU exact.
// Rows are 128B = 8 x 16B chunks; XOR pre-swizzle chunk^(row&7) on the DMA source,
// same XOR on the LDS read -> 2 lanes/bank-group (free).
template <int BM, int MINW, int ACT, bool RES, bool OUTB>
__global__ __launch_bounds__(256, MINW) void k_gemm(const bf16* __restrict__ A,
                                                    const bf16* __restrict__ Bt,
                                                    const float* __restrict__ bias,
                                                    const float* __restrict__ resid,
                                                    float* __restrict__ Cf,
                                                    bf16* __restrict__ Cb,
                                                    int M, int N, int K) {
  __shared__ __align__(16) bf16 As[2][BM * 64];
  __shared__ __align__(16) bf16 Bs[2][128 * 64];
  constexpr int NJ = (BM == 128) ? 4 : 2;
  const int tid = threadIdx.x;
  const int lane = tid & 63, wave = tid >> 6;
  const int quad = lane >> 4, c = lane & 15;
  // XCD-chunked bijective swizzle (grid % 8 == 0 at every call site)
  const int gx = gridDim.x;
  const int G  = gx * gridDim.y;
  const int bid = blockIdx.y * gx + blockIdx.x;
  const int wgid = (bid & 7) * (G >> 3) + (bid >> 3);
  const int bx = wgid % gx, by = wgid / gx;
  const int n0 = bx * 128, m0 = by * BM;

  const int wrb = (BM == 128) ? (wave >> 1) * 64 : 0;        // wave M base
  const int wcb = (BM == 128) ? (wave & 1) * 64 : wave * 32; // wave N base

  // staging: 1KB DMA instr = 8 rows x 128B; lane l covers row srow=l>>3, chunk l&7,
  // XOR pre-swizzled on the global source (all row groups stride 8 -> row&7 == srow).
  const int srow = lane >> 3;                                // 0..7
  const int gch  = (((lane & 7) ^ srow) << 3);               // elems
  const bf16* gA0;
  int ldsA0;
  if constexpr (BM == 128) {
    gA0 = A + (size_t)(m0 + wave * 32 + srow) * K + gch;     // 4 instrs: rows +0,8,16,24
    ldsA0 = wave * 2048;
  } else {
    gA0 = A + (size_t)(m0 + wave * 16 + srow) * K + gch;     // 2 instrs: rows +0,8
    ldsA0 = wave * 1024;
  }
  const bf16* gB0 = Bt + (size_t)(n0 + wave * 32 + srow) * K + gch;  // 4 instrs
  const int ldsB0 = wave * 2048;

  // loop-invariant LDS read chunk offsets: k-slice kk chunk = kk*4+quad, XOR row&7 (=c&7)
  const int xk0 = ((quad ^ (c & 7)) << 3);
  const int xk1 = (((quad | 4) ^ (c & 7)) << 3);
  int aRow[4], bRow[NJ];
#pragma unroll
  for (int i = 0; i < 4; ++i) aRow[i] = (wrb + i * 16 + c) * 64;
#pragma unroll
  for (int j = 0; j < NJ; ++j) bRow[j] = (wcb + j * 16 + c) * 64;

  floatx4 acc[4][NJ];
#pragma unroll
  for (int i = 0; i < 4; ++i)
#pragma unroll
    for (int j = 0; j < NJ; ++j) acc[i][j] = floatx4{0.f, 0.f, 0.f, 0.f};

  auto stage = [&](int buf, int k0) {
    if constexpr (BM == 128) {
#pragma unroll
      for (int p = 0; p < 4; ++p)
        gl2lds16(gA0 + k0 + (size_t)(8 * p) * K, &As[buf][ldsA0 + 512 * p]);
    } else {
#pragma unroll
      for (int p = 0; p < 2; ++p)
        gl2lds16(gA0 + k0 + (size_t)(8 * p) * K, &As[buf][ldsA0 + 512 * p]);
    }
#pragma unroll
    for (int p = 0; p < 4; ++p)
      gl2lds16(gB0 + k0 + (size_t)(8 * p) * K, &Bs[buf][ldsB0 + 512 * p]);
  };

  stage(0, 0);
  int cur = 0;
  for (int k0 = 0; k0 < K; k0 += 64) {
    // implicit vmcnt(0)+lgkmcnt(0) drain: buf[cur] staged data visible to all
    // waves; all waves done reading buf[cur^1] (this iteration's stage target).
    __syncthreads();
    if (k0 + 64 < K) stage(cur ^ 1, k0 + 64);
    bf16x8 af[4], bfv[NJ];
    // ---- k-slice 0 (k0..k0+32)
#pragma unroll
    for (int i = 0; i < 4; ++i) af[i] = *(const bf16x8*)(&As[cur][aRow[i] + xk0]);
#pragma unroll
    for (int j = 0; j < NJ; ++j) bfv[j] = *(const bf16x8*)(&Bs[cur][bRow[j] + xk0]);
#pragma unroll
    for (int i = 0; i < 4; ++i)
#pragma unroll
      for (int j = 0; j < NJ; ++j)
        acc[i][j] = MFMA16(af[i], bfv[j], acc[i][j]);
    // ---- k-slice 1 (k0+32..k0+64)
#pragma unroll
    for (int i = 0; i < 4; ++i) af[i] = *(const bf16x8*)(&As[cur][aRow[i] + xk1]);
#pragma unroll
    for (int j = 0; j < NJ; ++j) bfv[j] = *(const bf16x8*)(&Bs[cur][bRow[j] + xk1]);
#pragma unroll
    for (int i = 0; i < 4; ++i)
#pragma unroll
      for (int j = 0; j < NJ; ++j)
        acc[i][j] = MFMA16(af[i], bfv[j], acc[i][j]);
    cur ^= 1;
  }

  const int rbase = m0 + wrb + quad * 4;
  const int cbase = n0 + wcb + c;
#pragma unroll
  for (int i = 0; i < 4; ++i) {
#pragma unroll
    for (int j = 0; j < NJ; ++j) {
      const int col = cbase + j * 16;
      const float bc = bias[col];
#pragma unroll
      for (int r = 0; r < 4; ++r) {
        const int row = rbase + i * 16 + r;
        float v = acc[i][j][r] + bc;
        if (RES) v += resid[(size_t)row * N + col];
        if (ACT == 1) v = 0.5f * v * (1.f + erff(v * 0.70710678118654752f));
        if (ACT == 2) v = fmaxf(v, 0.f);
        if (OUTB) Cb[(size_t)row * N + col] = (bf16)v;
        else      Cf[(size_t)row * N + col] = v;
      }
    }
  }
  (void)M;
}

// ---- V transpose per head (single batch): vt[h*64 + d][s] = qkv_b[s, 1536 + h*64 + d] ----
__global__ __launch_bounds__(256) void k_vtrans(const bf16* __restrict__ qkv_b, bf16* __restrict__ vt) {
  __shared__ bf16 tile[64][72];
  const int tid = threadIdx.x;
  const int blk = blockIdx.x;
  const int h  = blk >> 7;       // 0..11
  const int st = blk & 127;
  const int s0 = st * 64;
  {
    const int d = tid & 63, si4 = tid >> 6;
    const bf16* src = qkv_b + (size_t)s0 * 2304 + 1536 + h * 64 + d;
#pragma unroll
    for (int i = 0; i < 16; ++i) {
      int s = si4 * 16 + i;
      tile[s][d] = src[(size_t)s * 2304];
    }
  }
  __syncthreads();
  {
    const int s = tid & 63, di4 = tid >> 6;
#pragma unroll
    for (int i = 0; i < 16; ++i) {
      int d = di4 * 16 + i;
      vt[((size_t)(h * 64 + d)) * SLEN + s0 + s] = tile[s][d];
    }
  }
}

// ---------------- band attention (single batch), flash-style, cooperative block ----------------
__global__ __launch_bounds__(256, 4) void k_attn(const bf16* __restrict__ qkv_b,
                                                 const bf16* __restrict__ vt,
                                                 bf16* __restrict__ aout_b) {
  __shared__ __align__(16) bf16 Ks[2][64 * 64];
  __shared__ __align__(16) bf16 Vs[2][64 * 64];
  __shared__ __align__(16) bf16 Ps[4][16 * 64];
  const int tid  = threadIdx.x;
  const int wave = tid >> 6, lane = tid & 63;
  const int quad = lane >> 4, c = lane & 15;
  // XCD-chunked swizzle: 1536 blocks % 8 XCDs == 0
  const int blk0 = blockIdx.x;
  const int wg   = ((blk0 & 7) * 192) + (blk0 >> 3);
  const int h    = wg >> 7;           // 0..11
  const int st   = wg & 127;
  const int q0b  = st * 64;
  const int q0   = q0b + wave * 16;

  const bf16* qp = qkv_b + (size_t)(q0 + c) * 2304 + h * 64 + quad * 8;
  const bf16x8 aq0 = *(const bf16x8*)(qp);
  const bf16x8 aq1 = *(const bf16x8*)(qp + 32);

  const int srow  = lane >> 3;                       // 0..7
  const int chunk = ((lane & 7) ^ srow) << 3;        // XOR pre-swizzle on global source
  const int krow0 = wave * 16 + srow;

  const int xlo = (quad ^ (c & 7)) << 3;
  const int xhi = ((quad + 4) ^ (c & 7)) << 3;

  floatx4 o[4];
  float m[4], l[4];
#pragma unroll
  for (int r = 0; r < 4; ++r) {
    o[r] = floatx4{0.f, 0.f, 0.f, 0.f};
    m[r] = -1e30f; l[r] = 0.f;
  }
  bf16* Pw = &Ps[wave][0];

  const int t_lo = st < 4 ? 4 - st : 0;
  const int t_hi = st > 123 ? 132 - st : 9;

  auto stage = [&](int buf, int t) {
    const int kb  = q0b - 256 + 64 * t;
    const int kr0 = iclamp(kb + krow0, 0, SLEN - 1);
    const int kr1 = iclamp(kb + krow0 + 8, 0, SLEN - 1);
    gl2lds16(qkv_b + (size_t)kr0 * 2304 + 768 + h * 64 + chunk, &Ks[buf][wave * 1024]);
    gl2lds16(qkv_b + (size_t)kr1 * 2304 + 768 + h * 64 + chunk, &Ks[buf][wave * 1024 + 512]);
    const int kbc = iclamp(kb, 0, SLEN - 64);
    gl2lds16(vt + (size_t)(h * 64 + krow0) * SLEN + kbc + chunk, &Vs[buf][wave * 1024]);
    gl2lds16(vt + (size_t)(h * 64 + krow0 + 8) * SLEN + kbc + chunk, &Vs[buf][wave * 1024 + 512]);
  };

  int cur = 0;
  stage(0, t_lo);
  for (int t = t_lo; t < t_hi; ++t) {
    __syncthreads();
    if (t + 1 < t_hi) stage(cur ^ 1, t + 1);
    const int kb = q0b - 256 + 64 * t;
    const bf16* Kb = &Ks[cur][0];
    const bf16* Vb = &Vs[cur][0];

    floatx4 s[4];
#pragma unroll
    for (int i = 0; i < 4; ++i) s[i] = floatx4{0.f, 0.f, 0.f, 0.f};
#pragma unroll
    for (int ks = 0; ks < 4; ++ks) {
      const bf16* kr = Kb + (ks * 16 + c) * 64;
      s[ks] = MFMA16(aq0, *(const bf16x8*)(kr + xlo), s[ks]);
      s[ks] = MFMA16(aq1, *(const bf16x8*)(kr + xhi), s[ks]);
    }
    if (t == 0 || t == 8) {
#pragma unroll
      for (int ks = 0; ks < 4; ++ks)
#pragma unroll
        for (int r = 0; r < 4; ++r) {
          int d = (kb + ks * 16 + c) - (q0 + quad * 4 + r);
          d = d < 0 ? -d : d;
          if (d > 256) s[ks][r] = -INFINITY;
        }
    }

    float tm[4], rs[4];
#pragma unroll
    for (int r = 0; r < 4; ++r)
      tm[r] = fmaxf(fmaxf(s[0][r], s[1][r]), fmaxf(s[2][r], s[3][r]));
#pragma unroll
    for (int off = 1; off < 16; off <<= 1)
#pragma unroll
      for (int r = 0; r < 4; ++r) tm[r] = fmaxf(tm[r], __shfl_xor(tm[r], off));
#pragma unroll
    for (int r = 0; r < 4; ++r) {
      const float mn = fmaxf(m[r], tm[r]);
      const float al = __expf(m[r] - mn);
      m[r] = mn;
      float sum = 0.f;
#pragma unroll
      for (int ks = 0; ks < 4; ++ks) { s[ks][r] = __expf(s[ks][r] - mn); sum += s[ks][r]; }
      rs[r] = sum;
      l[r] *= al;
#pragma unroll
      for (int n = 0; n < 4; ++n) o[n][r] *= al;
    }
#pragma unroll
    for (int off = 1; off < 16; off <<= 1)
#pragma unroll
      for (int r = 0; r < 4; ++r) rs[r] += __shfl_xor(rs[r], off);
#pragma unroll
    for (int r = 0; r < 4; ++r) l[r] += rs[r];

#pragma unroll
    for (int ks = 0; ks < 4; ++ks)
#pragma unroll
      for (int r = 0; r < 4; ++r) {
        const int prow = quad * 4 + r;
        const int col  = ks * 16 + c;
        Pw[prow * 64 + ((((col >> 3) ^ (prow & 7)) << 3) | (col & 7))] = (bf16)s[ks][r];
      }
    asm volatile("s_waitcnt lgkmcnt(0)" ::: "memory");
    const bf16x8 pa0 = *(const bf16x8*)(Pw + c * 64 + xlo);
    const bf16x8 pa1 = *(const bf16x8*)(Pw + c * 64 + xhi);
#pragma unroll
    for (int n = 0; n < 4; ++n) {
      const bf16* vr = Vb + (n * 16 + c) * 64;
      o[n] = MFMA16(pa0, *(const bf16x8*)(vr + xlo), o[n]);
      o[n] = MFMA16(pa1, *(const bf16x8*)(vr + xhi), o[n]);
    }
    cur ^= 1;
  }

#pragma unroll
  for (int r = 0; r < 4; ++r) {
    const float inv = 1.f / l[r];
    const size_t orow = (size_t)(q0 + quad * 4 + r) * BD + h * 64;
#pragma unroll
    for (int n = 0; n < 4; ++n)
      aout_b[orow + n * 16 + c] = (bf16)(o[n][r] * inv);
  }
}

extern "C" void kernel_launch(void* const* d_in, const int* in_sizes, int n_in,
                              void* d_out, int out_size, void* d_ws, size_t ws_size,
                              hipStream_t stream) {
  (void)in_sizes; (void)n_in; (void)out_size; (void)ws_size;
  const float* src     = (const float*)d_in[0];
  const float* pos_emb = (const float*)d_in[1];
  const float* tt_emb  = (const float*)d_in[2];
  const float* emb_s   = (const float*)d_in[3];
  const float* emb_b   = (const float*)d_in[4];
  const float* wq      = (const float*)d_in[5];
  const float* bq      = (const float*)d_in[6];
  const float* wk      = (const float*)d_in[7];
  const float* bk      = (const float*)d_in[8];
  const float* wv      = (const float*)d_in[9];
  const float* bv      = (const float*)d_in[10];
  const float* wo      = (const float*)d_in[11];
  const float* bo      = (const float*)d_in[12];
  const float* atn_s   = (const float*)d_in[13];
  const float* atn_b   = (const float*)d_in[14];
  const float* wi      = (const float*)d_in[15];
  const float* bi      = (const float*)d_in[16];
  const float* wo2     = (const float*)d_in[17];
  const float* bo2     = (const float*)d_in[18];
  const float* out_s   = (const float*)d_in[19];
  const float* out_b   = (const float*)d_in[20];
  const float* n1_s    = (const float*)d_in[21];
  const float* n1_b    = (const float*)d_in[22];
  const float* n2_s    = (const float*)d_in[23];
  const float* n2_b    = (const float*)d_in[24];
  const float* w1      = (const float*)d_in[25];
  const float* b1      = (const float*)d_in[26];
  const float* w2      = (const float*)d_in[27];
  const float* b2      = (const float*)d_in[28];

  char* ws = (char*)d_ws;
  size_t off = 0;
  auto alloc = [&](size_t bytes) {
    char* p = ws + off;
    off += (bytes + 255) & ~(size_t)255;
    return p;
  };

  // ---- persistent weights (~23.6 MB) ----
  bf16* qkvt  = (bf16*)alloc((size_t)2304 * 768 * 2);
  bf16* wot   = (bf16*)alloc((size_t)768 * 768 * 2);
  bf16* wit   = (bf16*)alloc((size_t)3072 * 768 * 2);
  bf16* wo2t  = (bf16*)alloc((size_t)768 * 3072 * 2);
  bf16* w1t   = (bf16*)alloc((size_t)3072 * 768 * 2);
  bf16* w2t   = (bf16*)alloc((size_t)768 * 3072 * 2);
  float* qkvb = (float*)alloc((size_t)2304 * 4);
  // ---- reusable regions (total ws ~155 MB) ----
  char* R1 = alloc((size_t)NTOK * BD * 4);                 // f32: h -> h2 -> src2
  char* R2 = alloc((size_t)NTOK * BD * 2);                 // bf16: hb -> h2b -> tb
  char* R3 = alloc((size_t)HTOK * 2304 * 2                 // per-batch qkv
                 + (size_t)NH * 64 * SLEN * 2              // per-batch vt
                 + (size_t)HTOK * BD * 2);                 // per-batch aout

  float* h_f   = (float*)R1;
  bf16*  hb    = (bf16*)R2;
  bf16*  qkvB  = (bf16*)R3;
  bf16*  vtB   = (bf16*)(R3 + (size_t)HTOK * 2304 * 2);
  bf16*  aoutB = (bf16*)(R3 + (size_t)HTOK * 2304 * 2 + (size_t)NH * 64 * SLEN * 2);
  float* y1    = (float*)d_out;
  float* h2f   = (float*)R1;
  bf16*  h2b   = (bf16*)R2;
  bf16*  interC= (bf16*)R3;
  float* y2    = (float*)d_out;
  float* src2  = (float*)R1;
  bf16*  tb    = (bf16*)R2;
  bf16*  ff1C  = (bf16*)R3;
  float* outp  = (float*)d_out;

  dim3 blk(256);
  // weight conversion (scale folds q /sqrt(64))
  k_prep_w<<<dim3(24, 24), blk, 0, stream>>>(wq, qkvt,                 768, 768, 0.125f);
  k_prep_w<<<dim3(24, 24), blk, 0, stream>>>(wk, qkvt + 768 * 768,     768, 768, 1.f);
  k_prep_w<<<dim3(24, 24), blk, 0, stream>>>(wv, qkvt + 2 * 768 * 768, 768, 768, 1.f);
  k_prep_w<<<dim3(24, 24), blk, 0, stream>>>(wo, wot,                  768, 768, 1.f);
  k_prep_w<<<dim3(96, 24), blk, 0, stream>>>(wi, wit,    768, 3072, 1.f);
  k_prep_w<<<dim3(24, 96), blk, 0, stream>>>(wo2, wo2t, 3072, 768,  1.f);
  k_prep_w<<<dim3(96, 24), blk, 0, stream>>>(w1, w1t,    768, 3072, 1.f);
  k_prep_w<<<dim3(24, 96), blk, 0, stream>>>(w2, w2t,   3072, 768,  1.f);
  k_prep_qkv_bias<<<dim3(9), blk, 0, stream>>>(bq, bk, bv, qkvb);

  // hidden = LN(src); h = LN(hidden + pos + tt)
  k_ln_ln_emb<<<dim3(NTOK), blk, 0, stream>>>(src, pos_emb, tt_emb, n1_s, n1_b,
                                              emb_s, emb_b, h_f, hb);
  // attention path, one batch at a time
  for (int b = 0; b < 2; ++b) {
    const size_t tok0 = (size_t)b * HTOK;
    k_gemm<128, 2, 0, false, true><<<dim3(18, 64), blk, 0, stream>>>(
        hb + tok0 * BD, qkvt, qkvb, nullptr, nullptr, qkvB, HTOK, 2304, 768);
    k_vtrans<<<dim3(NH * 128), blk, 0, stream>>>(qkvB, vtB);
    k_attn<<<dim3(NH * 128), blk, 0, stream>>>(qkvB, vtB, aoutB);
    k_gemm<64, 3, 0, true, false><<<dim3(6, 128), blk, 0, stream>>>(
        aoutB, wot, bo, h_f + tok0 * BD, y1 + tok0 * BD, nullptr, HTOK, 768, 768);
  }
  // h2 = LN(y1)
  k_ln<<<dim3(NTOK), blk, 0, stream>>>(y1, atn_s, atn_b, 1e-12f, h2f, h2b);
  // FFN, half the tokens at a time
  for (int cchunk = 0; cchunk < 2; ++cchunk) {
    const size_t tok0 = (size_t)cchunk * HTOK;
    k_gemm<128, 2, 1, false, true><<<dim3(24, 64), blk, 0, stream>>>(
        h2b + tok0 * BD, wit, bi, nullptr, nullptr, interC, HTOK, 3072, 768);
    k_gemm<64, 3, 0, true, false><<<dim3(6, 128), blk, 0, stream>>>(
        interC, wo2t, bo2, h2f + tok0 * BD, y2 + tok0 * BD, nullptr, HTOK, 768, 3072);
  }
  // out = LN(y2); src2 = src + out; t = LN(src2)
  k_ln_add_ln<<<dim3(NTOK), blk, 0, stream>>>(y2, src, out_s, out_b, n2_s, n2_b, src2, tb);
  // second FFN block
  for (int cchunk = 0; cchunk < 2; ++cchunk) {
    const size_t tok0 = (size_t)cchunk * HTOK;
    k_gemm<128, 2, 2, false, true><<<dim3(24, 64), blk, 0, stream>>>(
        tb + tok0 * BD, w1t, b1, nullptr, nullptr, ff1C, HTOK, 3072, 768);
    k_gemm<64, 3, 0, true, false><<<dim3(6, 128), blk, 0, stream>>>(
        ff1C, w2t, b2, src2 + tok0 * BD, outp + tok0 * BD, nullptr, HTOK, 768, 3072);
  }
}